// Round 9
// baseline (151.390 us; speedup 1.0000x reference)
//
#include <hip/hip_runtime.h>

// Problem constants: B=4, T=1024, F=500, H=128, P=64
// All external buffers fp32. Internal GEMMs bf16 (fp32 MFMA accum).
// out = [probs (B*T*P=262144), all_states (T*B*H=524288)] fp32
//
// LDS layout in GEMMs: XOR-swizzled, no padding. 16-B chunk `ch` of row r is
// stored at chunk index ch ^ (r & 7); row stride is a multiple of 32 words,
// so staging writes and MFMA fragment reads are bank-permutations.
//
// ws layout:
//   gi_bf   [0,        3145728)  4096x384 bf16
//   S_bf    [3145728,  4194304)  4096x128 bf16 ([T,B,H] rows sr=t*4+b)
//   Wc      [4194304,  6291456)  64x128x128 bf16 (folded ctx weights)
//   partial [6291456, 23068672)  8 x 4096x128 fp32 (ctx split-K partials)

typedef short bf16x8 __attribute__((ext_vector_type(8)));
typedef float f32x4 __attribute__((ext_vector_type(4)));
typedef unsigned short u16;
typedef unsigned int u32;

__device__ __forceinline__ float bf2f(u16 u) {
  union { u32 i; float f; } v; v.i = ((u32)u) << 16; return v.f;
}
__device__ __forceinline__ u16 f2bf(float f) {
  union { float f; u32 i; } v; v.f = f;
  u32 u = v.i;
  return (u16)((u + 0x7FFFu + ((u >> 16) & 1u)) >> 16);
}
__device__ __forceinline__ u32 pack2(float a, float b) {
  return (u32)f2bf(a) | ((u32)f2bf(b) << 16);
}
__device__ __forceinline__ float sigmoidf_(float x) {
  return 1.0f / (1.0f + __expf(-x));
}

// Wc[p][h'][h] = W_ctx[h', 8192 + h*64 + p] (+ part1 row sums folded into
// p==0), via coalesced loads + LDS transpose. 128 blocks (one per h').
__global__ __launch_bounds__(256) void k_prep(const float* __restrict__ W_ctx,
                                              u16* __restrict__ Wc) {
  const int tid = threadIdx.x;
  __shared__ float t1[128][68];   // part1 [h][q], +4 pad
  __shared__ float t2[128][68];   // part2 [h][p]
  __shared__ float s1[128];
  const int hp = blockIdx.x;
  const float* wrow = W_ctx + hp * 16384;
  for (int it = 0; it < 8; ++it) {
    int i = it * 256 + tid;
    int j = i * 4;
    int h = j >> 6, q = j & 63;
    *(float4*)&t1[h][q] = *(const float4*)(wrow + j);
    *(float4*)&t2[h][q] = *(const float4*)(wrow + 8192 + j);
  }
  __syncthreads();
  if (tid < 128) {
    float s = 0.f;
    for (int q = 0; q < 64; ++q) s += t1[tid][q];
    s1[tid] = s;
  }
  __syncthreads();
  for (int it = 0; it < 8; ++it) {
    int i = it * 256 + tid;
    int p = i >> 5, h0 = (i & 31) * 4;
    float v0 = t2[h0 + 0][p], v1 = t2[h0 + 1][p];
    float v2 = t2[h0 + 2][p], v3 = t2[h0 + 3][p];
    if (p == 0) { v0 += s1[h0]; v1 += s1[h0 + 1]; v2 += s1[h0 + 2]; v3 += s1[h0 + 3]; }
    uint2 o; o.x = pack2(v0, v1); o.y = pack2(v2, v3);
    *(uint2*)(Wc + p * 16384 + hp * 128 + h0) = o;
  }
}

// gi = x @ W_ih^T  (M=4096, N=384, K=500 zero-padded to 512 in LDS).
// Grid (64, 3), 256 threads. Block 64x128, wave-tile 64x32, BK=64, dbuf LDS
// (48 KB, XOR-swizzled). fp32 inputs converted to bf16 inline during staging
// (2x float4 -> pack -> uint4); x row stride 2000 B is 16B-aligned.
__global__ __launch_bounds__(256, 2) void k_gemm_gi(const float* __restrict__ x,
                                                    const float* __restrict__ W_ih,
                                                    u16* __restrict__ gi_bf) {
  __shared__ u16 Asm[2][64][64];    // [row][swizzled 8 chunks of 8 u16]
  __shared__ u16 Bsm[2][128][64];
  const int tid = threadIdx.x;
  const int w = tid >> 6, lane = tid & 63;
  const int l15 = lane & 15, quad = lane >> 4;
  const int m0 = blockIdx.x * 64;
  const int n0 = blockIdx.y * 128;
  f32x4 acc[4][2];
  for (int i = 0; i < 4; ++i)
    for (int j = 0; j < 2; ++j) acc[i][j] = (f32x4){0.f, 0.f, 0.f, 0.f};

  uint4 ra[2], rb[4];
  auto cvt_load = [](const float* base, int k) -> uint4 {
    float4 a = make_float4(0.f, 0.f, 0.f, 0.f), b = a;
    if (k < 500)     a = *(const float4*)(base + k);
    if (k + 4 < 500) b = *(const float4*)(base + k + 4);
    uint4 o; o.x = pack2(a.x, a.y); o.y = pack2(a.z, a.w);
    o.z = pack2(b.x, b.y); o.w = pack2(b.z, b.w);
    return o;
  };
  auto load_step = [&](int s) {
    int kc = s * 64;
#pragma unroll
    for (int j = 0; j < 2; ++j) {     // A: 64 rows x 8 chunks
      int c = j * 256 + tid;
      ra[j] = cvt_load(x + (size_t)(m0 + (c >> 3)) * 500, kc + (c & 7) * 8);
    }
#pragma unroll
    for (int j = 0; j < 4; ++j) {     // B: 128 rows x 8 chunks
      int c = j * 256 + tid;
      rb[j] = cvt_load(W_ih + (size_t)(n0 + (c >> 3)) * 500, kc + (c & 7) * 8);
    }
  };
  auto write_step = [&](int b) {
#pragma unroll
    for (int j = 0; j < 2; ++j) {
      int c = j * 256 + tid;
      int r = c >> 3, pc = (c & 7) ^ (r & 7);
      *(uint4*)&Asm[b][r][pc * 8] = ra[j];
    }
#pragma unroll
    for (int j = 0; j < 4; ++j) {
      int c = j * 256 + tid;
      int r = c >> 3, pc = (c & 7) ^ (r & 7);
      *(uint4*)&Bsm[b][r][pc * 8] = rb[j];
    }
  };

  load_step(0); write_step(0); __syncthreads();
  for (int s = 0; s < 8; ++s) {
    int cur = s & 1;
    if (s < 7) load_step(s + 1);
#pragma unroll
    for (int kk = 0; kk < 2; ++kk) {
      int ch = kk * 4 + quad;
      bf16x8 af[4], bfr[2];
#pragma unroll
      for (int mt = 0; mt < 4; ++mt) {
        int r = mt * 16 + l15;
        af[mt] = *(const bf16x8*)&Asm[cur][r][(ch ^ (r & 7)) * 8];
      }
#pragma unroll
      for (int nt = 0; nt < 2; ++nt) {
        int r = w * 32 + nt * 16 + l15;
        bfr[nt] = *(const bf16x8*)&Bsm[cur][r][(ch ^ (r & 7)) * 8];
      }
#pragma unroll
      for (int mt = 0; mt < 4; ++mt)
#pragma unroll
        for (int nt = 0; nt < 2; ++nt)
          acc[mt][nt] = __builtin_amdgcn_mfma_f32_16x16x32_bf16(af[mt], bfr[nt], acc[mt][nt], 0, 0, 0);
    }
    if (s < 7) write_step((s + 1) & 1);
    __syncthreads();
  }
  for (int mt = 0; mt < 4; ++mt)
    for (int nt = 0; nt < 2; ++nt)
      for (int rg = 0; rg < 4; ++rg) {
        int m = m0 + mt * 16 + quad * 4 + rg;    // C/D: row=(lane>>4)*4+reg
        int n = n0 + w * 32 + nt * 16 + l15;     //      col=lane&15
        gi_bf[m * 384 + n] = f2bf(acc[mt][nt][rg]);
      }
}

// GRU gates with h=0: s = (1-sig(gz+bz)) * tanh(gn + sig(gr+br)*bn_hh).
__global__ void k_states(const u16* __restrict__ gi_bf,
                         const float* __restrict__ b_ih, const float* __restrict__ b_hh,
                         u16* __restrict__ S_bf, float* __restrict__ out_states) {
  int g = blockIdx.x * 256 + threadIdx.x;  // 4096*128
  int r = g >> 7, h = g & 127;
  float xr = bf2f(gi_bf[r * 384 + h])       + b_ih[h]       + b_hh[h];
  float xz = bf2f(gi_bf[r * 384 + 128 + h]) + b_ih[128 + h] + b_hh[128 + h];
  float xn = bf2f(gi_bf[r * 384 + 256 + h]) + b_ih[256 + h];
  float rg = sigmoidf_(xr);
  float zg = sigmoidf_(xz);
  float n = tanhf(xn + rg * b_hh[256 + h]);
  float s = (1.f - zg) * n;
  int b = r >> 10, t = r & 1023;
  S_bf[(t * 4 + b) * 128 + h] = f2bf(s);
  out_states[(t * 4 + b) * 128 + h] = s;
}

// Context GEMM: partial[chunk][m][h'] = sum_{p in chunk of 8} Wc_p @ s[max(t-p,0),b].
// Grid (64 m-tiles of 64 rows, 8 p-chunks), 256 threads (2x2 wave grid,
// wave-tile 32m x 64n). The A union over the chunk's 8 shifts is a 92-row
// window staged ONCE (23 KB LDS); only B streams (16 KB/step, dbuf,
// 16 steps = 8 p x 2 k-halves, one barrier/step).
__global__ __launch_bounds__(256, 2) void k_gemm_ctx(const u16* __restrict__ S_bf,
                                                     const u16* __restrict__ Wc,
                                                     float* __restrict__ partial) {
  __shared__ u16 Awin[92][128];     // [window row][swizzled 16 chunks]
  __shared__ u16 Bsm[2][128][64];   // [dbuf][n][swizzled 8 chunks]
  const int tid = threadIdx.x;
  const int w = tid >> 6, lane = tid & 63;
  const int l15 = lane & 15, quad = lane >> 4;
  const int wm = (w & 1) * 32, wn = (w >> 1) * 64;
  const int m0 = blockIdx.x * 64;
  const int P0 = blockIdx.y * 8;
  const int t0 = m0 >> 2;
  const int tlo = t0 - P0 - 7;      // may be negative; rows clamp to s[0]
  f32x4 acc[2][4];
  for (int i = 0; i < 2; ++i)
    for (int j = 0; j < 4; ++j) acc[i][j] = (f32x4){0.f, 0.f, 0.f, 0.f};

  // Stage A window: row r holds s[max(tlo + (r>>2), 0), b=r&3][:], swizzled.
  for (int it = 0; it < 6; ++it) {
    int idx = it * 256 + tid;       // 92 rows x 16 chunks = 1472
    if (idx < 1472) {
      int r = idx >> 4, ch = idx & 15;
      int t = tlo + (r >> 2); if (t < 0) t = 0;
      uint4 v = *(const uint4*)(S_bf + (size_t)(t * 4 + (r & 3)) * 128 + ch * 8);
      *(uint4*)&Awin[r][((ch & 7) ^ (r & 7) | (ch & 8)) * 8] = v;
    }
  }
  uint4 rb[4];
  auto load_b = [&](int s) {        // step s: p = P0 + s/2, k-half = s&1
    const u16* wp = Wc + (size_t)(P0 + (s >> 1)) * 16384 + (s & 1) * 64;
#pragma unroll
    for (int j = 0; j < 4; ++j) {
      int c = j * 256 + tid;
      rb[j] = *(const uint4*)(wp + (c >> 3) * 128 + (c & 7) * 8);
    }
  };
  auto write_b = [&](int b) {
#pragma unroll
    for (int j = 0; j < 4; ++j) {
      int c = j * 256 + tid;
      int r = c >> 3, pc = (c & 7) ^ (r & 7);
      *(uint4*)&Bsm[b][r][pc * 8] = rb[j];
    }
  };

  load_b(0); write_b(0); __syncthreads();
  for (int s = 0; s < 16; ++s) {
    int cur = s & 1;
    if (s < 15) load_b(s + 1);
    const int shift = 4 * (7 - (s >> 1));   // A window row offset for this p
    const int kh = (s & 1) * 8;             // chunk offset of this k-half
#pragma unroll
    for (int kk = 0; kk < 2; ++kk) {
      int bch = kk * 4 + quad;              // B chunk 0..7
      int ach = kh + bch;                   // A chunk 0..15
      bf16x8 af[2], bfr[4];
#pragma unroll
      for (int mt = 0; mt < 2; ++mt) {
        int r = wm + mt * 16 + l15 + shift;
        af[mt] = *(const bf16x8*)&Awin[r][(((ach & 7) ^ (r & 7)) | (ach & 8)) * 8];
      }
#pragma unroll
      for (int nt = 0; nt < 4; ++nt) {
        int r = wn + nt * 16 + l15;
        bfr[nt] = *(const bf16x8*)&Bsm[cur][r][(bch ^ (r & 7)) * 8];
      }
#pragma unroll
      for (int mt = 0; mt < 2; ++mt)
#pragma unroll
        for (int nt = 0; nt < 4; ++nt)
          acc[mt][nt] = __builtin_amdgcn_mfma_f32_16x16x32_bf16(af[mt], bfr[nt], acc[mt][nt], 0, 0, 0);
    }
    if (s < 15) write_b((s + 1) & 1);
    __syncthreads();
  }
  float* op = partial + (size_t)blockIdx.y * 524288;
  for (int mt = 0; mt < 2; ++mt)
    for (int nt = 0; nt < 4; ++nt)
      for (int rg = 0; rg < 4; ++rg) {
        int m = m0 + wm + mt * 16 + quad * 4 + rg;
        int n = wn + nt * 16 + l15;
        op[m * 128 + n] = acc[mt][nt][rg];
      }
}

// Reduce 8 partials + b_ctx -> sigmoid gate; gated = states(fp32)*gate; FC+sig+clip.
__global__ __launch_bounds__(256) void k_epilogue(const float* __restrict__ partial,
                                                  const float* __restrict__ states,
                                                  const float* __restrict__ b_ctx,
                                                  const float* __restrict__ W_fc,
                                                  const float* __restrict__ b_fc,
                                                  float* __restrict__ out_probs) {
  __shared__ float WfcT[128][68];   // [h][p'] transposed, conflict-free dot
  __shared__ float gated[8][128];
  const int tid = threadIdx.x;
  const int row0 = blockIdx.x * 8;
  for (int it = 0; it < 32; ++it) {
    int i = it * 256 + tid;
    int pp = i >> 7, h = i & 127;
    WfcT[h][pp] = W_fc[i];
  }
  for (int it = 0; it < 4; ++it) {
    int i = it * 256 + tid;
    int lr = i >> 7, h = i & 127;
    int sr = row0 + lr;
    float gp = b_ctx[h];
#pragma unroll
    for (int c = 0; c < 8; ++c) gp += partial[(size_t)c * 524288 + sr * 128 + h];
    gated[lr][h] = states[sr * 128 + h] * sigmoidf_(gp);
  }
  __syncthreads();
  for (int it = 0; it < 2; ++it) {
    int o = it * 256 + tid;
    int lr = o >> 6, pp = o & 63;
    int sr = row0 + lr;
    float dot = 0.f;
#pragma unroll
    for (int h = 0; h < 128; ++h) dot += gated[lr][h] * WfcT[h][pp];
    float pv = sigmoidf_(dot + b_fc[pp]);
    pv = (pv > 0.001f) ? pv : 0.001f;
    pv = (pv < 0.999f) ? pv : 0.999f;
    int t = sr >> 2, b = sr & 3;
    out_probs[(b * 1024 + t) * 64 + pp] = pv;
  }
}

extern "C" void kernel_launch(void* const* d_in, const int* in_sizes, int n_in,
                              void* d_out, int out_size, void* d_ws, size_t ws_size,
                              hipStream_t stream) {
  const float* x     = (const float*)d_in[0];
  const float* W_ih  = (const float*)d_in[1];
  // d_in[2] = W_hh: unused (hidden state is always 0 in the reference)
  const float* b_ih  = (const float*)d_in[3];
  const float* b_hh  = (const float*)d_in[4];
  const float* W_ctx = (const float*)d_in[5];
  const float* b_ctx = (const float*)d_in[6];
  const float* W_fc  = (const float*)d_in[7];
  const float* b_fc  = (const float*)d_in[8];
  float* out = (float*)d_out;

  char* ws = (char*)d_ws;
  u16*   gi_bf   = (u16*)  (ws + 0);          // 3,145,728 B
  u16*   S_bf    = (u16*)  (ws + 3145728);    // 1,048,576 B
  u16*   Wc      = (u16*)  (ws + 4194304);    // 2,097,152 B
  float* partial = (float*)(ws + 6291456);    // 16,777,216 B
  // total ws used: 23,068,672 bytes

  k_prep<<<128, 256, 0, stream>>>(W_ctx, Wc);
  k_gemm_gi<<<dim3(64, 3), 256, 0, stream>>>(x, W_ih, gi_bf);
  k_states<<<2048, 256, 0, stream>>>(gi_bf, b_ih, b_hh, S_bf, out + 262144);
  k_gemm_ctx<<<dim3(64, 8), 256, 0, stream>>>(S_bf, Wc, partial);
  k_epilogue<<<512, 256, 0, stream>>>(partial, out + 262144, b_ctx, W_fc, b_fc, out);
}

// Round 10
// 141.735 us; speedup vs baseline: 1.0681x; 1.0681x over previous
//
#include <hip/hip_runtime.h>

// Problem constants: B=4, T=1024, F=500, H=128, P=64
// All external buffers fp32. Internal GEMMs bf16 (fp32 MFMA accum).
// out = [probs (B*T*P=262144), all_states (T*B*H=524288)] fp32
//
// LDS layout in GEMMs: XOR-swizzled, no padding. 16-B chunk `ch` of row r is
// stored at chunk index ch ^ (r & 7); row stride is a multiple of 32 words,
// so staging writes and MFMA fragment reads are bank-permutations.
// Both GEMMs: 512 threads (8 waves, 2x4 wave grid, wave-tile 32m x 32n)
// to maximize independently-stalling waves per CU (16/CU at 2 blocks/CU).
//
// ws layout:
//   gi_bf   [0,        3145728)  4096x384 bf16
//   S_bf    [3145728,  4194304)  4096x128 bf16 ([T,B,H] rows sr=t*4+b)
//   Wc      [4194304,  6291456)  64x128x128 bf16 (folded ctx weights)
//   partial [6291456, 23068672)  8 x 4096x128 fp32 (ctx split-K partials)

typedef short bf16x8 __attribute__((ext_vector_type(8)));
typedef float f32x4 __attribute__((ext_vector_type(4)));
typedef unsigned short u16;
typedef unsigned int u32;

__device__ __forceinline__ float bf2f(u16 u) {
  union { u32 i; float f; } v; v.i = ((u32)u) << 16; return v.f;
}
__device__ __forceinline__ u16 f2bf(float f) {
  union { float f; u32 i; } v; v.f = f;
  u32 u = v.i;
  return (u16)((u + 0x7FFFu + ((u >> 16) & 1u)) >> 16);
}
__device__ __forceinline__ u32 pack2(float a, float b) {
  return (u32)f2bf(a) | ((u32)f2bf(b) << 16);
}
__device__ __forceinline__ float sigmoidf_(float x) {
  return 1.0f / (1.0f + __expf(-x));
}

// Wc[p][h'][h] = W_ctx[h', 8192 + h*64 + p] (+ part1 row sums folded into
// p==0), via coalesced loads + LDS transpose. 128 blocks (one per h').
__global__ __launch_bounds__(256) void k_prep(const float* __restrict__ W_ctx,
                                              u16* __restrict__ Wc) {
  const int tid = threadIdx.x;
  __shared__ float t1[128][68];   // part1 [h][q], +4 pad
  __shared__ float t2[128][68];   // part2 [h][p]
  __shared__ float s1[128];
  const int hp = blockIdx.x;
  const float* wrow = W_ctx + hp * 16384;
  for (int it = 0; it < 8; ++it) {
    int i = it * 256 + tid;
    int j = i * 4;
    int h = j >> 6, q = j & 63;
    *(float4*)&t1[h][q] = *(const float4*)(wrow + j);
    *(float4*)&t2[h][q] = *(const float4*)(wrow + 8192 + j);
  }
  __syncthreads();
  if (tid < 128) {
    float s = 0.f;
    for (int q = 0; q < 64; ++q) s += t1[tid][q];
    s1[tid] = s;
  }
  __syncthreads();
  for (int it = 0; it < 8; ++it) {
    int i = it * 256 + tid;
    int p = i >> 5, h0 = (i & 31) * 4;
    float v0 = t2[h0 + 0][p], v1 = t2[h0 + 1][p];
    float v2 = t2[h0 + 2][p], v3 = t2[h0 + 3][p];
    if (p == 0) { v0 += s1[h0]; v1 += s1[h0 + 1]; v2 += s1[h0 + 2]; v3 += s1[h0 + 3]; }
    uint2 o; o.x = pack2(v0, v1); o.y = pack2(v2, v3);
    *(uint2*)(Wc + p * 16384 + hp * 128 + h0) = o;
  }
}

// gi = x @ W_ih^T  (M=4096, N=384, K=500 zero-padded to 512 in LDS).
// Grid (64, 3), 512 threads (8 waves, 2x4, wave-tile 32x32). Block 64x128,
// BK=64, dbuf LDS (48 KB, XOR-swizzled). fp32 inputs converted inline.
__global__ __launch_bounds__(512, 4) void k_gemm_gi(const float* __restrict__ x,
                                                    const float* __restrict__ W_ih,
                                                    u16* __restrict__ gi_bf) {
  __shared__ u16 Asm[2][64][64];    // [row][swizzled 8 chunks of 8 u16]
  __shared__ u16 Bsm[2][128][64];
  const int tid = threadIdx.x;
  const int w = tid >> 6, lane = tid & 63;
  const int l15 = lane & 15, quad = lane >> 4;
  const int wm = (w & 1) * 32, wn = (w >> 1) * 32;
  const int m0 = blockIdx.x * 64;
  const int n0 = blockIdx.y * 128;
  f32x4 acc[2][2];
  for (int i = 0; i < 2; ++i)
    for (int j = 0; j < 2; ++j) acc[i][j] = (f32x4){0.f, 0.f, 0.f, 0.f};

  uint4 ra, rb[2];
  auto cvt_load = [](const float* base, int k) -> uint4 {
    float4 a = make_float4(0.f, 0.f, 0.f, 0.f), b = a;
    if (k < 500)     a = *(const float4*)(base + k);
    if (k + 4 < 500) b = *(const float4*)(base + k + 4);
    uint4 o; o.x = pack2(a.x, a.y); o.y = pack2(a.z, a.w);
    o.z = pack2(b.x, b.y); o.w = pack2(b.z, b.w);
    return o;
  };
  auto load_step = [&](int s) {
    int kc = s * 64;
    {   // A: 64 rows x 8 chunks = 512, 1/thread
      int c = tid;
      ra = cvt_load(x + (size_t)(m0 + (c >> 3)) * 500, kc + (c & 7) * 8);
    }
#pragma unroll
    for (int j = 0; j < 2; ++j) {   // B: 128 rows x 8 chunks = 1024, 2/thread
      int c = j * 512 + tid;
      rb[j] = cvt_load(W_ih + (size_t)(n0 + (c >> 3)) * 500, kc + (c & 7) * 8);
    }
  };
  auto write_step = [&](int b) {
    {
      int c = tid;
      int r = c >> 3, pc = (c & 7) ^ (r & 7);
      *(uint4*)&Asm[b][r][pc * 8] = ra;
    }
#pragma unroll
    for (int j = 0; j < 2; ++j) {
      int c = j * 512 + tid;
      int r = c >> 3, pc = (c & 7) ^ (r & 7);
      *(uint4*)&Bsm[b][r][pc * 8] = rb[j];
    }
  };

  load_step(0); write_step(0); __syncthreads();
  for (int s = 0; s < 8; ++s) {
    int cur = s & 1;
    if (s < 7) load_step(s + 1);
#pragma unroll
    for (int kk = 0; kk < 2; ++kk) {
      int ch = kk * 4 + quad;
      bf16x8 af[2], bfr[2];
#pragma unroll
      for (int mt = 0; mt < 2; ++mt) {
        int r = wm + mt * 16 + l15;
        af[mt] = *(const bf16x8*)&Asm[cur][r][(ch ^ (r & 7)) * 8];
      }
#pragma unroll
      for (int nt = 0; nt < 2; ++nt) {
        int r = wn + nt * 16 + l15;
        bfr[nt] = *(const bf16x8*)&Bsm[cur][r][(ch ^ (r & 7)) * 8];
      }
#pragma unroll
      for (int mt = 0; mt < 2; ++mt)
#pragma unroll
        for (int nt = 0; nt < 2; ++nt)
          acc[mt][nt] = __builtin_amdgcn_mfma_f32_16x16x32_bf16(af[mt], bfr[nt], acc[mt][nt], 0, 0, 0);
    }
    if (s < 7) write_step((s + 1) & 1);
    __syncthreads();
  }
  for (int mt = 0; mt < 2; ++mt)
    for (int nt = 0; nt < 2; ++nt)
      for (int rg = 0; rg < 4; ++rg) {
        int m = m0 + wm + mt * 16 + quad * 4 + rg;   // C/D: row=(lane>>4)*4+reg
        int n = n0 + wn + nt * 16 + l15;             //      col=lane&15
        gi_bf[m * 384 + n] = f2bf(acc[mt][nt][rg]);
      }
}

// GRU gates with h=0: s = (1-sig(gz+bz)) * tanh(gn + sig(gr+br)*bn_hh).
__global__ void k_states(const u16* __restrict__ gi_bf,
                         const float* __restrict__ b_ih, const float* __restrict__ b_hh,
                         u16* __restrict__ S_bf, float* __restrict__ out_states) {
  int g = blockIdx.x * 256 + threadIdx.x;  // 4096*128
  int r = g >> 7, h = g & 127;
  float xr = bf2f(gi_bf[r * 384 + h])       + b_ih[h]       + b_hh[h];
  float xz = bf2f(gi_bf[r * 384 + 128 + h]) + b_ih[128 + h] + b_hh[128 + h];
  float xn = bf2f(gi_bf[r * 384 + 256 + h]) + b_ih[256 + h];
  float rg = sigmoidf_(xr);
  float zg = sigmoidf_(xz);
  float n = tanhf(xn + rg * b_hh[256 + h]);
  float s = (1.f - zg) * n;
  int b = r >> 10, t = r & 1023;
  S_bf[(t * 4 + b) * 128 + h] = f2bf(s);
  out_states[(t * 4 + b) * 128 + h] = s;
}

// Context GEMM: partial[chunk][m][h'] = sum_{p in chunk of 8} Wc_p @ s[max(t-p,0),b].
// Grid (64 m-tiles of 64 rows, 8 p-chunks), 512 threads (8 waves, 2x4 wave
// grid, wave-tile 32m x 32n). The A union over the chunk's 8 shifts is a
// 92-row window staged ONCE (23 KB LDS); only B streams (16 KB/step, dbuf,
// 16 steps = 8 p x 2 k-halves, one barrier/step). 56 KB LDS -> 2 blocks/CU
// -> 16 waves/CU for latency interleave.
__global__ __launch_bounds__(512, 4) void k_gemm_ctx(const u16* __restrict__ S_bf,
                                                     const u16* __restrict__ Wc,
                                                     float* __restrict__ partial) {
  __shared__ u16 Awin[92][128];     // [window row][swizzled 16 chunks]
  __shared__ u16 Bsm[2][128][64];   // [dbuf][n][swizzled 8 chunks]
  const int tid = threadIdx.x;
  const int w = tid >> 6, lane = tid & 63;
  const int l15 = lane & 15, quad = lane >> 4;
  const int wm = (w & 1) * 32, wn = (w >> 1) * 32;
  const int m0 = blockIdx.x * 64;
  const int P0 = blockIdx.y * 8;
  const int t0 = m0 >> 2;
  const int tlo = t0 - P0 - 7;      // may be negative; rows clamp to s[0]
  f32x4 acc[2][2];
  for (int i = 0; i < 2; ++i)
    for (int j = 0; j < 2; ++j) acc[i][j] = (f32x4){0.f, 0.f, 0.f, 0.f};

  // Stage A window: row r holds s[max(tlo + (r>>2), 0), b=r&3][:], swizzled.
  for (int it = 0; it < 3; ++it) {
    int idx = it * 512 + tid;       // 92 rows x 16 chunks = 1472
    if (idx < 1472) {
      int r = idx >> 4, ch = idx & 15;
      int t = tlo + (r >> 2); if (t < 0) t = 0;
      uint4 v = *(const uint4*)(S_bf + (size_t)(t * 4 + (r & 3)) * 128 + ch * 8);
      *(uint4*)&Awin[r][(((ch & 7) ^ (r & 7)) | (ch & 8)) * 8] = v;
    }
  }
  uint4 rb[2];
  auto load_b = [&](int s) {        // step s: p = P0 + s/2, k-half = s&1
    const u16* wp = Wc + (size_t)(P0 + (s >> 1)) * 16384 + (s & 1) * 64;
#pragma unroll
    for (int j = 0; j < 2; ++j) {   // 1024 chunks, 2/thread
      int c = j * 512 + tid;
      rb[j] = *(const uint4*)(wp + (c >> 3) * 128 + (c & 7) * 8);
    }
  };
  auto write_b = [&](int b) {
#pragma unroll
    for (int j = 0; j < 2; ++j) {
      int c = j * 512 + tid;
      int r = c >> 3, pc = (c & 7) ^ (r & 7);
      *(uint4*)&Bsm[b][r][pc * 8] = rb[j];
    }
  };

  load_b(0); write_b(0); __syncthreads();
  for (int s = 0; s < 16; ++s) {
    int cur = s & 1;
    if (s < 15) load_b(s + 1);
    const int shift = 4 * (7 - (s >> 1));   // A window row offset for this p
    const int kh = (s & 1) * 8;             // chunk offset of this k-half
#pragma unroll
    for (int kk = 0; kk < 2; ++kk) {
      int bch = kk * 4 + quad;              // B chunk 0..7
      int ach = kh + bch;                   // A chunk 0..15
      bf16x8 af[2], bfr[2];
#pragma unroll
      for (int mt = 0; mt < 2; ++mt) {
        int r = wm + mt * 16 + l15 + shift;
        af[mt] = *(const bf16x8*)&Awin[r][(((ach & 7) ^ (r & 7)) | (ach & 8)) * 8];
      }
#pragma unroll
      for (int nt = 0; nt < 2; ++nt) {
        int r = wn + nt * 16 + l15;
        bfr[nt] = *(const bf16x8*)&Bsm[cur][r][(bch ^ (r & 7)) * 8];
      }
#pragma unroll
      for (int mt = 0; mt < 2; ++mt)
#pragma unroll
        for (int nt = 0; nt < 2; ++nt)
          acc[mt][nt] = __builtin_amdgcn_mfma_f32_16x16x32_bf16(af[mt], bfr[nt], acc[mt][nt], 0, 0, 0);
    }
    if (s < 15) write_b((s + 1) & 1);
    __syncthreads();
  }
  float* op = partial + (size_t)blockIdx.y * 524288;
  for (int mt = 0; mt < 2; ++mt)
    for (int nt = 0; nt < 2; ++nt)
      for (int rg = 0; rg < 4; ++rg) {
        int m = m0 + wm + mt * 16 + quad * 4 + rg;
        int n = wn + nt * 16 + l15;
        op[m * 128 + n] = acc[mt][nt][rg];
      }
}

// Reduce 8 partials + b_ctx -> sigmoid gate; gated = states(fp32)*gate; FC+sig+clip.
__global__ __launch_bounds__(256) void k_epilogue(const float* __restrict__ partial,
                                                  const float* __restrict__ states,
                                                  const float* __restrict__ b_ctx,
                                                  const float* __restrict__ W_fc,
                                                  const float* __restrict__ b_fc,
                                                  float* __restrict__ out_probs) {
  __shared__ float WfcT[128][68];   // [h][p'] transposed, conflict-free dot
  __shared__ float gated[8][128];
  const int tid = threadIdx.x;
  const int row0 = blockIdx.x * 8;
  for (int it = 0; it < 32; ++it) {
    int i = it * 256 + tid;
    int pp = i >> 7, h = i & 127;
    WfcT[h][pp] = W_fc[i];
  }
  for (int it = 0; it < 4; ++it) {
    int i = it * 256 + tid;
    int lr = i >> 7, h = i & 127;
    int sr = row0 + lr;
    float gp = b_ctx[h];
#pragma unroll
    for (int c = 0; c < 8; ++c) gp += partial[(size_t)c * 524288 + sr * 128 + h];
    gated[lr][h] = states[sr * 128 + h] * sigmoidf_(gp);
  }
  __syncthreads();
  for (int it = 0; it < 2; ++it) {
    int o = it * 256 + tid;
    int lr = o >> 6, pp = o & 63;
    int sr = row0 + lr;
    float dot = 0.f;
#pragma unroll
    for (int h = 0; h < 128; ++h) dot += gated[lr][h] * WfcT[h][pp];
    float pv = sigmoidf_(dot + b_fc[pp]);
    pv = (pv > 0.001f) ? pv : 0.001f;
    pv = (pv < 0.999f) ? pv : 0.999f;
    int t = sr >> 2, b = sr & 3;
    out_probs[(b * 1024 + t) * 64 + pp] = pv;
  }
}

extern "C" void kernel_launch(void* const* d_in, const int* in_sizes, int n_in,
                              void* d_out, int out_size, void* d_ws, size_t ws_size,
                              hipStream_t stream) {
  const float* x     = (const float*)d_in[0];
  const float* W_ih  = (const float*)d_in[1];
  // d_in[2] = W_hh: unused (hidden state is always 0 in the reference)
  const float* b_ih  = (const float*)d_in[3];
  const float* b_hh  = (const float*)d_in[4];
  const float* W_ctx = (const float*)d_in[5];
  const float* b_ctx = (const float*)d_in[6];
  const float* W_fc  = (const float*)d_in[7];
  const float* b_fc  = (const float*)d_in[8];
  float* out = (float*)d_out;

  char* ws = (char*)d_ws;
  u16*   gi_bf   = (u16*)  (ws + 0);          // 3,145,728 B
  u16*   S_bf    = (u16*)  (ws + 3145728);    // 1,048,576 B
  u16*   Wc      = (u16*)  (ws + 4194304);    // 2,097,152 B
  float* partial = (float*)(ws + 6291456);    // 16,777,216 B
  // total ws used: 23,068,672 bytes

  k_prep<<<128, 256, 0, stream>>>(W_ctx, Wc);
  k_gemm_gi<<<dim3(64, 3), 512, 0, stream>>>(x, W_ih, gi_bf);
  k_states<<<2048, 256, 0, stream>>>(gi_bf, b_ih, b_hh, S_bf, out + 262144);
  k_gemm_ctx<<<dim3(64, 8), 512, 0, stream>>>(S_bf, Wc, partial);
  k_epilogue<<<512, 256, 0, stream>>>(partial, out + 262144, b_ctx, W_fc, b_fc, out);
}

// Round 11
// 119.499 us; speedup vs baseline: 1.2669x; 1.1861x over previous
//
#include <hip/hip_runtime.h>

// Problem constants: B=4, T=1024, F=500, H=128, P=64
// All external buffers fp32. Internal GEMMs bf16 (fp32 MFMA accum).
// out = [probs (B*T*P=262144), all_states (T*B*H=524288)] fp32
//
// LDS layout in GEMMs: XOR-swizzled, no padding. 16-B chunk `ch` of row r is
// stored at chunk index ch ^ (r & 7); row stride is a multiple of 32 words,
// so staging writes and MFMA fragment reads are bank-permutations.
//
// ws layout:
//   gi_bf   [0,        3145728)  4096x384 bf16
//   S_bf    [3145728,  4194304)  4096x128 bf16 ([T,B,H] rows sr=t*4+b)
//   Wc      [4194304,  6291456)  64x128x128 bf16 (folded ctx weights)
//   partial [6291456, 23068672)  8 x 4096x128 fp32 (ctx split-K partials)

typedef short bf16x8 __attribute__((ext_vector_type(8)));
typedef float f32x4 __attribute__((ext_vector_type(4)));
typedef unsigned short u16;
typedef unsigned int u32;

__device__ __forceinline__ float bf2f(u16 u) {
  union { u32 i; float f; } v; v.i = ((u32)u) << 16; return v.f;
}
__device__ __forceinline__ u16 f2bf(float f) {
  union { float f; u32 i; } v; v.f = f;
  u32 u = v.i;
  return (u16)((u + 0x7FFFu + ((u >> 16) & 1u)) >> 16);
}
__device__ __forceinline__ u32 pack2(float a, float b) {
  return (u32)f2bf(a) | ((u32)f2bf(b) << 16);
}
__device__ __forceinline__ float sigmoidf_(float x) {
  return 1.0f / (1.0f + __expf(-x));
}

// Wc[p][h'][h] = W_ctx[h', 8192 + h*64 + p] (+ part1 row sums folded into
// p==0), via coalesced loads + LDS transpose. 128 blocks (one per h').
__global__ __launch_bounds__(256) void k_prep(const float* __restrict__ W_ctx,
                                              u16* __restrict__ Wc) {
  const int tid = threadIdx.x;
  __shared__ float t1[128][68];   // part1 [h][q], +4 pad
  __shared__ float t2[128][68];   // part2 [h][p]
  __shared__ float s1[128];
  const int hp = blockIdx.x;
  const float* wrow = W_ctx + hp * 16384;
  for (int it = 0; it < 8; ++it) {
    int i = it * 256 + tid;
    int j = i * 4;
    int h = j >> 6, q = j & 63;
    *(float4*)&t1[h][q] = *(const float4*)(wrow + j);
    *(float4*)&t2[h][q] = *(const float4*)(wrow + 8192 + j);
  }
  __syncthreads();
  if (tid < 128) {
    float s = 0.f;
    for (int q = 0; q < 64; ++q) s += t1[tid][q];
    s1[tid] = s;
  }
  __syncthreads();
  for (int it = 0; it < 8; ++it) {
    int i = it * 256 + tid;
    int p = i >> 5, h0 = (i & 31) * 4;
    float v0 = t2[h0 + 0][p], v1 = t2[h0 + 1][p];
    float v2 = t2[h0 + 2][p], v3 = t2[h0 + 3][p];
    if (p == 0) { v0 += s1[h0]; v1 += s1[h0 + 1]; v2 += s1[h0 + 2]; v3 += s1[h0 + 3]; }
    uint2 o; o.x = pack2(v0, v1); o.y = pack2(v2, v3);
    *(uint2*)(Wc + p * 16384 + hp * 128 + h0) = o;
  }
}

// gi = x @ W_ih^T  (M=4096, N=384, K=500 zero-padded to 512 in LDS).
// Grid (64, 3), 512 threads (8 waves, 2x4, wave-tile 32x32). Block 64x128,
// BK=64, dbuf LDS (48 KB, XOR-swizzled). fp32 inputs converted inline.
__global__ __launch_bounds__(512, 4) void k_gemm_gi(const float* __restrict__ x,
                                                    const float* __restrict__ W_ih,
                                                    u16* __restrict__ gi_bf) {
  __shared__ u16 Asm[2][64][64];    // [row][swizzled 8 chunks of 8 u16]
  __shared__ u16 Bsm[2][128][64];
  const int tid = threadIdx.x;
  const int w = tid >> 6, lane = tid & 63;
  const int l15 = lane & 15, quad = lane >> 4;
  const int wm = (w & 1) * 32, wn = (w >> 1) * 32;
  const int m0 = blockIdx.x * 64;
  const int n0 = blockIdx.y * 128;
  f32x4 acc[2][2];
  for (int i = 0; i < 2; ++i)
    for (int j = 0; j < 2; ++j) acc[i][j] = (f32x4){0.f, 0.f, 0.f, 0.f};

  uint4 ra, rb[2];
  auto cvt_load = [](const float* base, int k) -> uint4 {
    float4 a = make_float4(0.f, 0.f, 0.f, 0.f), b = a;
    if (k < 500)     a = *(const float4*)(base + k);
    if (k + 4 < 500) b = *(const float4*)(base + k + 4);
    uint4 o; o.x = pack2(a.x, a.y); o.y = pack2(a.z, a.w);
    o.z = pack2(b.x, b.y); o.w = pack2(b.z, b.w);
    return o;
  };
  auto load_step = [&](int s) {
    int kc = s * 64;
    {   // A: 64 rows x 8 chunks = 512, 1/thread
      int c = tid;
      ra = cvt_load(x + (size_t)(m0 + (c >> 3)) * 500, kc + (c & 7) * 8);
    }
#pragma unroll
    for (int j = 0; j < 2; ++j) {   // B: 128 rows x 8 chunks = 1024, 2/thread
      int c = j * 512 + tid;
      rb[j] = cvt_load(W_ih + (size_t)(n0 + (c >> 3)) * 500, kc + (c & 7) * 8);
    }
  };
  auto write_step = [&](int b) {
    {
      int c = tid;
      int r = c >> 3, pc = (c & 7) ^ (r & 7);
      *(uint4*)&Asm[b][r][pc * 8] = ra;
    }
#pragma unroll
    for (int j = 0; j < 2; ++j) {
      int c = j * 512 + tid;
      int r = c >> 3, pc = (c & 7) ^ (r & 7);
      *(uint4*)&Bsm[b][r][pc * 8] = rb[j];
    }
  };

  load_step(0); write_step(0); __syncthreads();
  for (int s = 0; s < 8; ++s) {
    int cur = s & 1;
    if (s < 7) load_step(s + 1);
#pragma unroll
    for (int kk = 0; kk < 2; ++kk) {
      int ch = kk * 4 + quad;
      bf16x8 af[2], bfr[2];
#pragma unroll
      for (int mt = 0; mt < 2; ++mt) {
        int r = wm + mt * 16 + l15;
        af[mt] = *(const bf16x8*)&Asm[cur][r][(ch ^ (r & 7)) * 8];
      }
#pragma unroll
      for (int nt = 0; nt < 2; ++nt) {
        int r = wn + nt * 16 + l15;
        bfr[nt] = *(const bf16x8*)&Bsm[cur][r][(ch ^ (r & 7)) * 8];
      }
#pragma unroll
      for (int mt = 0; mt < 2; ++mt)
#pragma unroll
        for (int nt = 0; nt < 2; ++nt)
          acc[mt][nt] = __builtin_amdgcn_mfma_f32_16x16x32_bf16(af[mt], bfr[nt], acc[mt][nt], 0, 0, 0);
    }
    if (s < 7) write_step((s + 1) & 1);
    __syncthreads();
  }
  for (int mt = 0; mt < 2; ++mt)
    for (int nt = 0; nt < 2; ++nt)
      for (int rg = 0; rg < 4; ++rg) {
        int m = m0 + wm + mt * 16 + quad * 4 + rg;   // C/D: row=(lane>>4)*4+reg
        int n = n0 + wn + nt * 16 + l15;             //      col=lane&15
        gi_bf[m * 384 + n] = f2bf(acc[mt][nt][rg]);
      }
}

// GRU gates with h=0: s = (1-sig(gz+bz)) * tanh(gn + sig(gr+br)*bn_hh).
__global__ void k_states(const u16* __restrict__ gi_bf,
                         const float* __restrict__ b_ih, const float* __restrict__ b_hh,
                         u16* __restrict__ S_bf, float* __restrict__ out_states) {
  int g = blockIdx.x * 256 + threadIdx.x;  // 4096*128
  int r = g >> 7, h = g & 127;
  float xr = bf2f(gi_bf[r * 384 + h])       + b_ih[h]       + b_hh[h];
  float xz = bf2f(gi_bf[r * 384 + 128 + h]) + b_ih[128 + h] + b_hh[128 + h];
  float xn = bf2f(gi_bf[r * 384 + 256 + h]) + b_ih[256 + h];
  float rg = sigmoidf_(xr);
  float zg = sigmoidf_(xz);
  float n = tanhf(xn + rg * b_hh[256 + h]);
  float s = (1.f - zg) * n;
  int b = r >> 10, t = r & 1023;
  S_bf[(t * 4 + b) * 128 + h] = f2bf(s);
  out_states[(t * 4 + b) * 128 + h] = s;
}

// Context GEMM: partial[chunk][m][h'] = sum_{p in chunk of 8} Wc_p @ s[max(t-p,0),b].
// Grid (64 m-tiles, 2 n-halves, 8 p-chunks) = 1024 blocks, 512 threads
// (8 waves, 2x4 wave grid, wave-tile 32m x 16n). Block tile 64m x 64n.
// The A union over the chunk's 8 shifts is a 92-row window staged ONCE
// (23.5 KB); only B streams (8 KB/step, dbuf 16 KB, 16 steps, one
// barrier/step). 39.5 KB LDS -> 4 blocks/CU -> 32 waves/CU.
__global__ __launch_bounds__(512, 6) void k_gemm_ctx(const u16* __restrict__ S_bf,
                                                     const u16* __restrict__ Wc,
                                                     float* __restrict__ partial) {
  __shared__ u16 Awin[92][128];     // [window row][swizzled 16 chunks]
  __shared__ u16 Bsm[2][64][64];    // [dbuf][n within half][swizzled 8 chunks]
  const int tid = threadIdx.x;
  const int w = tid >> 6, lane = tid & 63;
  const int l15 = lane & 15, quad = lane >> 4;
  const int wm = (w & 1) * 32, wn = (w >> 1) * 16;
  const int m0 = blockIdx.x * 64;
  const int n0 = blockIdx.y * 64;
  const int P0 = blockIdx.z * 8;
  const int tlo = (m0 >> 2) - P0 - 7;   // may be negative; rows clamp to s[0]
  f32x4 acc[2];
  acc[0] = (f32x4){0.f, 0.f, 0.f, 0.f};
  acc[1] = (f32x4){0.f, 0.f, 0.f, 0.f};

  // Stage A window: row r holds s[max(tlo + (r>>2), 0), b=r&3][:], swizzled.
  for (int it = 0; it < 3; ++it) {
    int idx = it * 512 + tid;       // 92 rows x 16 chunks = 1472
    if (idx < 1472) {
      int r = idx >> 4, ch = idx & 15;
      int t = tlo + (r >> 2); if (t < 0) t = 0;
      uint4 v = *(const uint4*)(S_bf + (size_t)(t * 4 + (r & 3)) * 128 + ch * 8);
      *(uint4*)&Awin[r][(((ch & 7) ^ (r & 7)) | (ch & 8)) * 8] = v;
    }
  }
  uint4 rb;
  auto load_b = [&](int s) {        // step s: p = P0 + s/2, k-half = s&1
    const u16* wp = Wc + (size_t)(P0 + (s >> 1)) * 16384 + (s & 1) * 64;
    int c = tid;                    // 64 rows x 8 chunks = 512, 1/thread
    rb = *(const uint4*)(wp + (size_t)(n0 + (c >> 3)) * 128 + (c & 7) * 8);
  };
  auto write_b = [&](int b) {
    int c = tid;
    int r = c >> 3, pc = (c & 7) ^ (r & 7);
    *(uint4*)&Bsm[b][r][pc * 8] = rb;
  };

  load_b(0); write_b(0); __syncthreads();
  for (int s = 0; s < 16; ++s) {
    int cur = s & 1;
    if (s < 15) load_b(s + 1);
    const int shift = 4 * (7 - (s >> 1));   // A window row offset for this p
    const int kh = (s & 1) * 8;             // chunk offset of this k-half
#pragma unroll
    for (int kk = 0; kk < 2; ++kk) {
      int bch = kk * 4 + quad;              // B chunk 0..7
      int ach = kh + bch;                   // A chunk 0..15
      bf16x8 af[2], bf0;
#pragma unroll
      for (int mt = 0; mt < 2; ++mt) {
        int r = wm + mt * 16 + l15 + shift;
        af[mt] = *(const bf16x8*)&Awin[r][(((ach & 7) ^ (r & 7)) | (ach & 8)) * 8];
      }
      {
        int r = wn + l15;
        bf0 = *(const bf16x8*)&Bsm[cur][r][(bch ^ (r & 7)) * 8];
      }
#pragma unroll
      for (int mt = 0; mt < 2; ++mt)
        acc[mt] = __builtin_amdgcn_mfma_f32_16x16x32_bf16(af[mt], bf0, acc[mt], 0, 0, 0);
    }
    if (s < 15) write_b((s + 1) & 1);
    __syncthreads();
  }
  float* op = partial + (size_t)blockIdx.z * 524288;
#pragma unroll
  for (int mt = 0; mt < 2; ++mt)
#pragma unroll
    for (int rg = 0; rg < 4; ++rg) {
      int m = m0 + wm + mt * 16 + quad * 4 + rg;
      int n = n0 + wn + l15;
      op[m * 128 + n] = acc[mt][rg];
    }
}

// Reduce 8 partials + b_ctx -> sigmoid gate; gated = states(fp32)*gate; FC+sig+clip.
__global__ __launch_bounds__(256) void k_epilogue(const float* __restrict__ partial,
                                                  const float* __restrict__ states,
                                                  const float* __restrict__ b_ctx,
                                                  const float* __restrict__ W_fc,
                                                  const float* __restrict__ b_fc,
                                                  float* __restrict__ out_probs) {
  __shared__ float WfcT[128][68];   // [h][p'] transposed, conflict-free dot
  __shared__ float gated[8][128];
  const int tid = threadIdx.x;
  const int row0 = blockIdx.x * 8;
  for (int it = 0; it < 32; ++it) {
    int i = it * 256 + tid;
    int pp = i >> 7, h = i & 127;
    WfcT[h][pp] = W_fc[i];
  }
  for (int it = 0; it < 4; ++it) {
    int i = it * 256 + tid;
    int lr = i >> 7, h = i & 127;
    int sr = row0 + lr;
    float gp = b_ctx[h];
#pragma unroll
    for (int c = 0; c < 8; ++c) gp += partial[(size_t)c * 524288 + sr * 128 + h];
    gated[lr][h] = states[sr * 128 + h] * sigmoidf_(gp);
  }
  __syncthreads();
  for (int it = 0; it < 2; ++it) {
    int o = it * 256 + tid;
    int lr = o >> 6, pp = o & 63;
    int sr = row0 + lr;
    float dot = 0.f;
#pragma unroll
    for (int h = 0; h < 128; ++h) dot += gated[lr][h] * WfcT[h][pp];
    float pv = sigmoidf_(dot + b_fc[pp]);
    pv = (pv > 0.001f) ? pv : 0.001f;
    pv = (pv < 0.999f) ? pv : 0.999f;
    int t = sr >> 2, b = sr & 3;
    out_probs[(b * 1024 + t) * 64 + pp] = pv;
  }
}

extern "C" void kernel_launch(void* const* d_in, const int* in_sizes, int n_in,
                              void* d_out, int out_size, void* d_ws, size_t ws_size,
                              hipStream_t stream) {
  const float* x     = (const float*)d_in[0];
  const float* W_ih  = (const float*)d_in[1];
  // d_in[2] = W_hh: unused (hidden state is always 0 in the reference)
  const float* b_ih  = (const float*)d_in[3];
  const float* b_hh  = (const float*)d_in[4];
  const float* W_ctx = (const float*)d_in[5];
  const float* b_ctx = (const float*)d_in[6];
  const float* W_fc  = (const float*)d_in[7];
  const float* b_fc  = (const float*)d_in[8];
  float* out = (float*)d_out;

  char* ws = (char*)d_ws;
  u16*   gi_bf   = (u16*)  (ws + 0);          // 3,145,728 B
  u16*   S_bf    = (u16*)  (ws + 3145728);    // 1,048,576 B
  u16*   Wc      = (u16*)  (ws + 4194304);    // 2,097,152 B
  float* partial = (float*)(ws + 6291456);    // 16,777,216 B
  // total ws used: 23,068,672 bytes

  k_prep<<<128, 256, 0, stream>>>(W_ctx, Wc);
  k_gemm_gi<<<dim3(64, 3), 512, 0, stream>>>(x, W_ih, gi_bf);
  k_states<<<2048, 256, 0, stream>>>(gi_bf, b_ih, b_hh, S_bf, out + 262144);
  k_gemm_ctx<<<dim3(64, 2, 8), 512, 0, stream>>>(S_bf, Wc, partial);
  k_epilogue<<<512, 256, 0, stream>>>(partial, out + 262144, b_ctx, W_fc, b_fc, out);
}